// Round 1
// baseline (375.841 us; speedup 1.0000x reference)
//
#include <hip/hip_runtime.h>
#include <hip/hip_bf16.h>

#define Bz 4
#define Sz 2048
#define Dz 1024
#define Hz 16
#define DHz 64

typedef __bf16 bf16x8 __attribute__((ext_vector_type(8)));
typedef float f32x4 __attribute__((ext_vector_type(4)));
typedef short s16x4 __attribute__((ext_vector_type(4)));
typedef unsigned short u16x4 __attribute__((ext_vector_type(4)));

// LDS-only barrier: waits DS ops, leaves global loads in flight (unlike
// __syncthreads, which drains vmcnt(0) and defeats register prefetch).
#define BAR_LGKM() asm volatile("s_waitcnt lgkmcnt(0)\n\ts_barrier" ::: "memory")

// fp32 -> bf16 elementwise cast (RTN), n % 4 == 0.
__global__ __launch_bounds__(256) void cvt_f32_bf16(const float* __restrict__ src,
                                                    __hip_bfloat16* __restrict__ dst, int n) {
    int i = (blockIdx.x * 256 + threadIdx.x) * 4;
    if (i >= n) return;
    float4 f = *reinterpret_cast<const float4*>(src + i);
    dst[i + 0] = __float2bfloat16(f.x);
    dst[i + 1] = __float2bfloat16(f.y);
    dst[i + 2] = __float2bfloat16(f.z);
    dst[i + 3] = __float2bfloat16(f.w);
}

// 4 weight matrices (Dz*Dz each) -> contiguous bf16 dst in one launch.
__global__ __launch_bounds__(256) void cvt_w4(const float* __restrict__ w0, const float* __restrict__ w1,
                                              const float* __restrict__ w2, const float* __restrict__ w3,
                                              __hip_bfloat16* __restrict__ dst) {
    constexpr int WEL = Dz * Dz;  // 1<<20
    int i = (blockIdx.x * 256 + threadIdx.x) * 4;
    const int which = i >> 20;
    const float* src = (which == 0) ? w0 : (which == 1) ? w1 : (which == 2) ? w2 : w3;
    float4 f = *reinterpret_cast<const float4*>(src + (i & (WEL - 1)));
    dst[i + 0] = __float2bfloat16(f.x);
    dst[i + 1] = __float2bfloat16(f.y);
    dst[i + 2] = __float2bfloat16(f.z);
    dst[i + 3] = __float2bfloat16(f.w);
}

// async global -> LDS, 16 bytes per lane; LDS dest = uniform base + lane*16.
__device__ __forceinline__ void gl2lds16(const __hip_bfloat16* g, __hip_bfloat16* l) {
    __builtin_amdgcn_global_load_lds(
        (const __attribute__((address_space(1))) void*)g,
        (__attribute__((address_space(3))) void*)l, 16, 0, 0);
}

// Shared 128x128 GEMM block body (m97 structure, BK=32).
template <int N, int K, typename OT>
__device__ __forceinline__ void gemm128_body(const __hip_bfloat16* __restrict__ A,
                                             const __hip_bfloat16* __restrict__ W,
                                             OT* __restrict__ C, int bm, int bn,
                                             __hip_bfloat16* As, __hip_bfloat16* Bs) {
    const int tid  = threadIdx.x;
    const int wid  = tid >> 6;
    const int lane = tid & 63;
    const int quad = lane >> 4;
    const int l16  = lane & 15;
    const int wr = wid >> 1, wc = wid & 1;

    const int srow = wid * 32 + (lane >> 2);
    const int scol = (lane & 3) * 8;
    const __hip_bfloat16* gA = A + (size_t)(bm * 128 + srow) * K + scol;
    const __hip_bfloat16* gB = W + (size_t)(bn * 128 + srow) * K + scol;
    __hip_bfloat16* lA = &As[(wid * 32) * 32];
    __hip_bfloat16* lB = &Bs[(wid * 32) * 32];

    f32x4 acc[4][4] = {};

    for (int k0 = 0; k0 < K; k0 += 32) {
        __syncthreads();
        gl2lds16(gA + k0,                  lA);
        gl2lds16(gA + (size_t)16 * K + k0, lA + 16 * 32);
        gl2lds16(gB + k0,                  lB);
        gl2lds16(gB + (size_t)16 * K + k0, lB + 16 * 32);
        __syncthreads();

        bf16x8 af[4], bf[4];
#pragma unroll
        for (int mi = 0; mi < 4; ++mi)
            af[mi] = *reinterpret_cast<const bf16x8*>(&As[(wr * 64 + mi * 16 + l16) * 32 + quad * 8]);
#pragma unroll
        for (int ni = 0; ni < 4; ++ni)
            bf[ni] = *reinterpret_cast<const bf16x8*>(&Bs[(wc * 64 + ni * 16 + l16) * 32 + quad * 8]);
#pragma unroll
        for (int mi = 0; mi < 4; ++mi)
#pragma unroll
            for (int ni = 0; ni < 4; ++ni)
                acc[mi][ni] = __builtin_amdgcn_mfma_f32_16x16x32_bf16(af[mi], bf[ni], acc[mi][ni], 0, 0, 0);
    }

#pragma unroll
    for (int mi = 0; mi < 4; ++mi)
#pragma unroll
        for (int ni = 0; ni < 4; ++ni) {
            const size_t row0 = (size_t)(bm * 128 + wr * 64 + mi * 16 + quad * 4);
            const size_t col  = (size_t)(bn * 128 + wc * 64 + ni * 16 + l16);
#pragma unroll
            for (int r = 0; r < 4; ++r) {
                if constexpr (__is_same(OT, float))
                    C[(row0 + r) * N + col] = acc[mi][ni][r];
                else
                    C[(row0 + r) * N + col] = __float2bfloat16(acc[mi][ni][r]);
            }
        }
}

template <int M, int N, int K, typename OT>
__global__ __launch_bounds__(256) void gemm128(const __hip_bfloat16* __restrict__ A,
                                               const __hip_bfloat16* __restrict__ W,
                                               OT* __restrict__ C) {
    __shared__ __hip_bfloat16 As[128 * 32];
    __shared__ __hip_bfloat16 Bs[128 * 32];
    constexpr int NB = N / 128;
    gemm128_body<N, K, OT>(A, W, C, blockIdx.x / NB, blockIdx.x % NB, As, Bs);
}

// Fused QKV: grid = 3 * (M/128) * (Dz/128); which = blockIdx%3 so the 3 GEMMs
// sharing an A-tile are adjacent in dispatch order (L2 reuse of A).
template <int M, int K>
__global__ __launch_bounds__(256) void gemm_qkv(const __hip_bfloat16* __restrict__ A,
                                                const __hip_bfloat16* __restrict__ W0,
                                                const __hip_bfloat16* __restrict__ W1,
                                                const __hip_bfloat16* __restrict__ W2,
                                                __hip_bfloat16* __restrict__ C0,
                                                __hip_bfloat16* __restrict__ C1,
                                                __hip_bfloat16* __restrict__ C2) {
    __shared__ __hip_bfloat16 As[128 * 32];
    __shared__ __hip_bfloat16 Bs[128 * 32];
    constexpr int NB = Dz / 128;
    const int which = blockIdx.x % 3;
    const int rem   = blockIdx.x / 3;
    const __hip_bfloat16* W = (which == 0) ? W0 : (which == 1) ? W1 : W2;
    __hip_bfloat16*       C = (which == 0) ? C0 : (which == 1) ? C1 : C2;
    gemm128_body<Dz, K, __hip_bfloat16>(A, W, C, rem / NB, rem % NB, As, Bs);
}

// V^T leading stride (ushorts). 68 -> dword row stride 34 == 2 (mod 32): the 16
// row-starts of a b64 fragment read rotate by 2 banks -> uniform 4 dword
// accesses per bank per read instruction (minimum). Writes (b64) likewise uniform.
#define SV 68

// 16x16x16 bf16 MFMA: K=16 fragment layout (k = quad*4+j) matches the per-lane
// S^T score layout, so P^T feeds PV directly from registers (no LDS round-trip).
__device__ __forceinline__ f32x4 mfma16bf(s16x4 a, s16x4 b, f32x4 c) {
#if __has_builtin(__builtin_amdgcn_mfma_f32_16x16x16bf16_1k)
    return __builtin_amdgcn_mfma_f32_16x16x16bf16_1k(a, b, c, 0, 0, 0);
#else
    asm volatile("v_mfma_f32_16x16x16_bf16 %0, %1, %2, %0" : "+v"(c) : "v"(a), "v"(b));
    return c;
#endif
}

// MFMA flash attention v4:
//  - O^T accumulation (D = V^T · P^T): q lands in the D column = lane&15, which is
//    where softmax state (m, l) already lives -> alpha/l rescale and epilogue need
//    ZERO cross-lane shuffles (v3 spent 4 ds_bpermute/iter + 4 in epilogue).
//  - PV via 16x16x16 MFMA: B-operand (P^T) taken straight from the score regs;
//    the whole PT LDS buffer + write/readback round-trip is deleted.
//  - Double-buffered V^T in LDS -> ONE lgkm-only barrier per iteration (was 2).
//  - exp in log2 domain (scores * 0.125*log2e, v_exp_f32 directly).
//  - Skip O-rescale when no row max increased (alpha == 1 exactly; bit-identical).
__global__ __launch_bounds__(256) void attn_mfma4(const __hip_bfloat16* __restrict__ Q,
                                                  const __hip_bfloat16* __restrict__ Km,
                                                  const __hip_bfloat16* __restrict__ Vm,
                                                  __hip_bfloat16* __restrict__ O) {
    __shared__ unsigned short VT[2][64 * SV];     // V^T: [dh][key-local 0..63], double-buffered

    const int tid  = threadIdx.x;
    const int lane = tid & 63;
    const int wid  = tid >> 6;
    const int quad = lane >> 4;
    const int l16  = lane & 15;

    // XCD-local mapping: all 16 pair-blocks of a (b,h) share blockIdx%8 -> same XCD L2.
    const int xcd  = blockIdx.x & 7;
    const int j    = blockIdx.x >> 3;             // 0..127
    const int bh   = xcd * 8 + (j >> 4);          // 0..63
    const int pair = j & 15;
    const int h    = bh & 15;
    const int b    = bh >> 4;
    const size_t base = (size_t)b * Sz * Dz + (size_t)h * DHz;

    // V staging: thread owns keys vkey..vkey+3 at dh vdh..vdh+3 (4x 8B loads,
    // 4x b64 transposed LDS writes).
    const int vkey = (tid & 15) * 4;
    const int vdh  = (tid >> 4) * 4;
    const __hip_bfloat16* vbase = Vm + base + vdh;

    u16x4  vr[4];                                 // V prefetch regs (4 key-rows x 4 dh)
    bf16x8 kf[4][2];                              // K frags: 4 key-subtiles x 2 dh-halves

    auto loadKV = [&](int kn) {
#pragma unroll
        for (int k = 0; k < 4; ++k)
            vr[k] = *reinterpret_cast<const u16x4*>(vbase + (size_t)(kn + vkey + k) * Dz);
#pragma unroll
        for (int s = 0; s < 4; ++s) {
            const __hip_bfloat16* kp = Km + base + (size_t)(kn + s * 16 + l16) * Dz + quad * 8;
            kf[s][0] = *reinterpret_cast<const bf16x8*>(kp);
            kf[s][1] = *reinterpret_cast<const bf16x8*>(kp + 32);
        }
    };

    constexpr float SC = 0.18033688011112042f;    // 0.125 * log2(e)

    int buf = 0;                                  // persists across p: buffer alternation
                                                  // must not reset (single-barrier safety)
#pragma unroll 1
    for (int p = 0; p < 2; ++p) {
        const int qblk  = (p == 0) ? pair : 31 - pair;
        const int q0    = qblk * 64 + wid * 16;
        const int niter = qblk + 1;

        const __hip_bfloat16* qp = Q + base + (size_t)(q0 + l16) * Dz + quad * 8;
        const bf16x8 qf0 = *reinterpret_cast<const bf16x8*>(qp);
        const bf16x8 qf1 = *reinterpret_cast<const bf16x8*>(qp + 32);

        float m = -1e30f, l = 0.f;
        f32x4 ot[4] = {};                         // O^T: ot[sd][r] = O^T[dh=sd*16+quad*4+r][q=l16]

        if (p == 0) loadKV(0);                    // p==1 start tile prefetched at end of p==0

#pragma unroll 1
        for (int it = 0; it < niter; ++it) {
            const int k0 = it * 64;

            // stage V^T tile into VT[buf] from prefetch regs (b64 stores)
#pragma unroll
            for (int i = 0; i < 4; ++i) {
                u16x4 w;
                w[0] = vr[0][i]; w[1] = vr[1][i]; w[2] = vr[2][i]; w[3] = vr[3][i];
                *reinterpret_cast<u16x4*>(&VT[buf][(vdh + i) * SV + vkey]) = w;
            }
            BAR_LGKM();   // VT[buf] visible; prior buf-reads (2 bodies back) drained
                          // at the previous barrier -> one barrier/iter is safe.

            // S^T = K·Q^T : 8 MFMAs (K=32)
            f32x4 st[4] = {};
#pragma unroll
            for (int s = 0; s < 4; ++s) {
                st[s] = __builtin_amdgcn_mfma_f32_16x16x32_bf16(kf[s][0], qf0, st[s], 0, 0, 0);
                st[s] = __builtin_amdgcn_mfma_f32_16x16x32_bf16(kf[s][1], qf1, st[s], 0, 0, 0);
            }

            // prefetch next K/V tile — stays in flight across the lgkm barrier
            const bool more = (it + 1 < niter);
            if (more)        loadKV(k0 + 64);
            else if (p == 0) loadKV(0);

            // scores -> log2 domain; causal mask on diagonal tile only
            float sv[16];
            if (it == niter - 1) {                // block-uniform branch
                const int qrow = q0 + l16;
#pragma unroll
                for (int s = 0; s < 4; ++s)
#pragma unroll
                    for (int r = 0; r < 4; ++r) {
                        const int key = k0 + s * 16 + quad * 4 + r;
                        sv[s * 4 + r] = (key <= qrow) ? st[s][r] * SC : -1e30f;
                    }
            } else {
#pragma unroll
                for (int s = 0; s < 4; ++s)
#pragma unroll
                    for (int r = 0; r < 4; ++r) sv[s * 4 + r] = st[s][r] * SC;
            }

            // row max: tree reduce in-lane, then across quads
            float mx[8];
#pragma unroll
            for (int i = 0; i < 8; ++i) mx[i] = fmaxf(sv[2 * i], sv[2 * i + 1]);
#pragma unroll
            for (int i = 0; i < 4; ++i) mx[i] = fmaxf(mx[2 * i], mx[2 * i + 1]);
            float tmax = fmaxf(fmaxf(mx[0], mx[1]), fmaxf(mx[2], mx[3]));
            tmax = fmaxf(tmax, __shfl_xor(tmax, 16, 64));
            tmax = fmaxf(tmax, __shfl_xor(tmax, 32, 64));

            const float mnew = fmaxf(m, tmax);
            const bool  skip = __all(tmax <= m);  // no row raised its max -> alpha==1 exactly
            float alpha = 1.f;
            if (!skip) {
                alpha = __builtin_amdgcn_exp2f(m - mnew);
                m = mnew;
#pragma unroll
                for (int s = 0; s < 4; ++s) ot[s] *= alpha;   // own-lane alpha: q == l16
            }

            // P = exp2(sv - m); pack to bf16 P^T fragments in-register
            float pv[16];
#pragma unroll
            for (int i = 0; i < 16; ++i) pv[i] = __builtin_amdgcn_exp2f(sv[i] - m);

            s16x4 pw[4];
#pragma unroll
            for (int s = 0; s < 4; ++s)
#pragma unroll
                for (int r = 0; r < 4; ++r) {
                    union { __hip_bfloat16 hh; short uu; } cv;
                    cv.hh = __float2bfloat16(pv[s * 4 + r]);
                    pw[s][r] = cv.uu;
                }

            float ad[8];
#pragma unroll
            for (int i = 0; i < 8; ++i) ad[i] = pv[2 * i] + pv[2 * i + 1];
#pragma unroll
            for (int i = 0; i < 4; ++i) ad[i] = ad[2 * i] + ad[2 * i + 1];
            float psum = (ad[0] + ad[1]) + (ad[2] + ad[3]);
            psum += __shfl_xor(psum, 16, 64);
            psum += __shfl_xor(psum, 32, 64);
            l = l * alpha + psum;

            // PV: O^T[dh][q] += V^T[dh][key] · P^T[key][q]   (16x16x16, K=16)
            const unsigned short* vt = &VT[buf][0];
#pragma unroll
            for (int sd = 0; sd < 4; ++sd) {
                const unsigned short* vrow = vt + (sd * 16 + l16) * SV + quad * 4;
#pragma unroll
                for (int sk = 0; sk < 4; ++sk) {
                    const s16x4 vf = *reinterpret_cast<const s16x4*>(vrow + sk * 16);
                    ot[sd] = mfma16bf(vf, pw[sk], ot[sd]);
                }
            }
            buf ^= 1;
        }

        // epilogue: lane holds O^T[dh=sd*16+quad*4+r][q=l16]; l is own-lane.
        const float linv = 1.f / l;
        __hip_bfloat16* op = O + base + (size_t)(q0 + l16) * Dz + quad * 4;
#pragma unroll
        for (int sd = 0; sd < 4; ++sd) {
            u16x4 w;
#pragma unroll
            for (int r = 0; r < 4; ++r) {
                union { __hip_bfloat16 hh; unsigned short uu; } cv;
                cv.hh = __float2bfloat16(ot[sd][r] * linv);
                w[r] = cv.uu;
            }
            *reinterpret_cast<u16x4*>(op + sd * 16) = w;
        }
    }
}

extern "C" void kernel_launch(void* const* d_in, const int* in_sizes, int n_in,
                              void* d_out, int out_size, void* d_ws, size_t ws_size,
                              hipStream_t stream) {
    // Inputs fp32, output fp32. Internal compute bf16.
    const float* x  = (const float*)d_in[0];
    const float* wq = (const float*)d_in[1];
    const float* wk = (const float*)d_in[2];
    const float* wv = (const float*)d_in[3];
    const float* wo = (const float*)d_in[4];
    float* out = (float*)d_out;

    constexpr int TOK = Bz * Sz * Dz;   // 8,388,608
    constexpr int WEL = Dz * Dz;        // 1,048,576

    // ws: xb | wqb | wkb | wvb | wob | Qb | Kb (56 MB). Vb in d_out scratch; Ob aliases xb.
    __hip_bfloat16* xb  = (__hip_bfloat16*)d_ws;
    __hip_bfloat16* wqb = xb  + TOK;
    __hip_bfloat16* wkb = wqb + WEL;
    __hip_bfloat16* wvb = wkb + WEL;
    __hip_bfloat16* wob = wvb + WEL;
    __hip_bfloat16* Qb  = wob + WEL;
    __hip_bfloat16* Kb  = Qb + TOK;
    __hip_bfloat16* Vb  = (__hip_bfloat16*)d_out;  // dead before final GEMM overwrites d_out
    __hip_bfloat16* Ob  = xb;                      // x dead after QKV GEMM

    cvt_f32_bf16<<<TOK / 4 / 256, 256, 0, stream>>>(x, xb, TOK);
    cvt_w4<<<4 * WEL / 4 / 256, 256, 0, stream>>>(wq, wk, wv, wo, wqb);

    constexpr int M = Bz * Sz;                       // 8192
    constexpr int GB = (M / 128) * (Dz / 128);       // 512

    gemm_qkv<M, Dz><<<3 * GB, 256, 0, stream>>>(xb, wqb, wkb, wvb, Qb, Kb, Vb);

    const int ATTN_BLOCKS = Bz * Hz * 16;            // 1024 (paired q-blocks)
    attn_mfma4<<<ATTN_BLOCKS, 256, 0, stream>>>(Qb, Kb, Vb, Ob);

    gemm128<M, Dz, Dz, float><<<GB, 256, 0, stream>>>(Ob, wob, out);
}